// Round 3
// baseline (260.913 us; speedup 1.0000x reference)
//
#include <hip/hip_runtime.h>

#define B_NUM 64
#define C_NUM 4
#define J_NUM 17
#define HH 96
#define WW 96
#define HWSZ (HH * WW)  // 9216

__device__ __forceinline__ float waveMax(float v) {
#pragma unroll
  for (int o = 32; o > 0; o >>= 1) v = fmaxf(v, __shfl_xor(v, o));
  return v;
}
__device__ __forceinline__ float waveSum(float v) {
#pragma unroll
  for (int o = 32; o > 0; o >>= 1) v += __shfl_xor(v, o);
  return v;
}

// One block per (b, j). Wave `cam` (0..3) does the full softargmax for camera
// `cam`'s heatmap row (9216 fp32 = 36 float4/lane) with wave-level reductions
// only. Then thread 0 solves the 4x4 DLT eigenproblem (double Jacobi).
__global__ __launch_bounds__(256, 1) void triang_fused_k(
    const float* __restrict__ hm, const float* __restrict__ P,
    const float* __restrict__ conf, const int* __restrict__ Hp,
    const int* __restrict__ Wp, float* __restrict__ out) {
  const int bj = blockIdx.x;  // 0..1087
  const int b = bj / J_NUM;
  const int j = bj - b * J_NUM;
  const int t = threadIdx.x;
  const int cam = t >> 6;
  const int lane = t & 63;
  const int r = (b * C_NUM + cam) * J_NUM + j;
  const float4* row = (const float4*)(hm + (size_t)r * HWSZ);

  float4 v[36];
  float m = -3.4e38f;
#pragma unroll
  for (int k = 0; k < 36; ++k) {
    v[k] = row[k * 64 + lane];
    m = fmaxf(m, fmaxf(fmaxf(v[k].x, v[k].y), fmaxf(v[k].z, v[k].w)));
  }
  m = waveMax(m);
  const float M100 = 100.0f * m;

  float se = 0.f, sx = 0.f, sy = 0.f;
#pragma unroll
  for (int k = 0; k < 36; ++k) {
    const int base = k * 256 + lane * 4;  // 4 | 96 -> all 4 elems share h
    const float e0 = __expf(fmaf(100.f, v[k].x, -M100));
    const float e1 = __expf(fmaf(100.f, v[k].y, -M100));
    const float e2 = __expf(fmaf(100.f, v[k].z, -M100));
    const float e3 = __expf(fmaf(100.f, v[k].w, -M100));
    const int h = base / WW;
    const int w0 = base - h * WW;
    const float esum = (e0 + e1) + (e2 + e3);
    se += esum;
    sy += esum * (float)h;
    sx += e0 * (float)w0 + e1 * (float)(w0 + 1) + e2 * (float)(w0 + 2) +
          e3 * (float)(w0 + 3);
  }
  se = waveSum(se);
  sx = waveSum(sx);
  sy = waveSum(sy);

  __shared__ float skp[C_NUM][2];
  if (lane == 0) {
    // reference: scale = [H_img/Hh, W_img/Wh] applied to (kx, ky) in order
    const float scx = (float)Hp[0] / (float)HH;
    const float scy = (float)Wp[0] / (float)WW;
    skp[cam][0] = sx / se * scx;
    skp[cam][1] = sy / se * scy;
  }
  __syncthreads();
  if (t != 0) return;

  // ---- DLT: M = A^T A in double, 4x4 Jacobi eigen, min-eigenvalue vector ----
  double M4[4][4];
#pragma unroll
  for (int a = 0; a < 4; ++a)
#pragma unroll
    for (int bb = 0; bb < 4; ++bb) M4[a][bb] = 0.0;

#pragma unroll
  for (int c = 0; c < C_NUM; ++c) {
    const float* Pm = P + ((size_t)(b * C_NUM + c)) * 12;
    const float cf = conf[(b * C_NUM + c) * J_NUM + j];
    const double x = (double)skp[c][0];
    const double y = (double)skp[c][1];
    double row0[4], row1[4];
#pragma unroll
    for (int l = 0; l < 4; ++l) {
      const double p2 = (double)Pm[8 + l];
      row0[l] = (p2 * x - (double)Pm[l]) * (double)cf;
      row1[l] = (p2 * y - (double)Pm[4 + l]) * (double)cf;
    }
#pragma unroll
    for (int a = 0; a < 4; ++a)
#pragma unroll
      for (int bb = 0; bb < 4; ++bb)
        M4[a][bb] += row0[a] * row0[bb] + row1[a] * row1[bb];
  }

  double V[4][4];
#pragma unroll
  for (int a = 0; a < 4; ++a)
#pragma unroll
    for (int bb = 0; bb < 4; ++bb) V[a][bb] = (a == bb) ? 1.0 : 0.0;

  for (int sweep = 0; sweep < 8; ++sweep) {
#pragma unroll
    for (int p = 0; p < 3; ++p) {
#pragma unroll
      for (int q = p + 1; q < 4; ++q) {
        const double d = M4[p][q];
        if (fabs(d) < 1e-300) continue;
        const double a = M4[p][p], bq = M4[q][q];
        const double theta = (bq - a) / (2.0 * d);
        const double tt = (theta >= 0.0 ? 1.0 : -1.0) /
                          (fabs(theta) + sqrt(theta * theta + 1.0));
        const double cc = 1.0 / sqrt(tt * tt + 1.0);
        const double ss = tt * cc;
#pragma unroll
        for (int k = 0; k < 4; ++k) {
          if (k == p || k == q) continue;
          const double mkp = M4[k][p], mkq = M4[k][q];
          M4[k][p] = M4[p][k] = cc * mkp - ss * mkq;
          M4[k][q] = M4[q][k] = ss * mkp + cc * mkq;
        }
        M4[p][p] = a - tt * d;
        M4[q][q] = bq + tt * d;
        M4[p][q] = M4[q][p] = 0.0;
#pragma unroll
        for (int k = 0; k < 4; ++k) {
          const double vkp = V[k][p], vkq = V[k][q];
          V[k][p] = cc * vkp - ss * vkq;
          V[k][q] = ss * vkp + cc * vkq;
        }
      }
    }
  }

  int mi = 0;
  double mv = M4[0][0];
#pragma unroll
  for (int i = 1; i < 4; ++i)
    if (M4[i][i] < mv) { mv = M4[i][i]; mi = i; }
  const double h3 = V[3][mi];
  out[bj * 3 + 0] = (float)(V[0][mi] / h3);
  out[bj * 3 + 1] = (float)(V[1][mi] / h3);
  out[bj * 3 + 2] = (float)(V[2][mi] / h3);
}

extern "C" void kernel_launch(void* const* d_in, const int* in_sizes, int n_in,
                              void* d_out, int out_size, void* d_ws, size_t ws_size,
                              hipStream_t stream) {
  const float* hm = (const float*)d_in[0];
  const float* P = (const float*)d_in[1];
  const float* conf = (const float*)d_in[2];
  const int* Hp = (const int*)d_in[3];
  const int* Wp = (const int*)d_in[4];
  float* out = (float*)d_out;

  triang_fused_k<<<B_NUM * J_NUM, 256, 0, stream>>>(hm, P, conf, Hp, Wp, out);
}

// Round 4
// 241.985 us; speedup vs baseline: 1.0782x; 1.0782x over previous
//
#include <hip/hip_runtime.h>

#define B_NUM 64
#define C_NUM 4
#define J_NUM 17
#define HH 96
#define WW 96
#define HWSZ (HH * WW)  // 9216

__device__ __forceinline__ float waveMax(float v) {
#pragma unroll
  for (int o = 32; o > 0; o >>= 1) v = fmaxf(v, __shfl_xor(v, o));
  return v;
}
__device__ __forceinline__ float waveSum(float v) {
#pragma unroll
  for (int o = 32; o > 0; o >>= 1) v += __shfl_xor(v, o);
  return v;
}

// One block (256 threads) per (bc, j) row of 9216 fp32. Single pass with
// ONLINE softmax: per-thread running max m with branchless rescale, so no
// second consumption of loaded values (no remat / no spill; ~40 VGPR).
__global__ __launch_bounds__(256) void softargmax_k(
    const float* __restrict__ hm, const int* __restrict__ Hp,
    const int* __restrict__ Wp, float* __restrict__ kp) {
  const int r = blockIdx.x;
  const int t = threadIdx.x;
  const float4* row = (const float4*)(hm + (size_t)r * HWSZ);

  float m = -3.4e38f;  // exp(100*(m - mn)) underflows to 0 on first update
  float se = 0.f, sx = 0.f, sy = 0.f;
#pragma unroll
  for (int k = 0; k < 9; ++k) {
    const float4 v = row[k * 256 + t];
    const int base = k * 1024 + t * 4;  // 4 | 96 -> all 4 elems share h
    const int h = base / WW;
    const int w0 = base - h * WW;
    const float c = fmaxf(fmaxf(v.x, v.y), fmaxf(v.z, v.w));
    const float mn = fmaxf(m, c);
    const float f = __expf(100.f * (m - mn));  // 1.0 when no new max
    m = mn;
    se *= f; sx *= f; sy *= f;
    const float a = -100.f * mn;
    const float e0 = __expf(fmaf(100.f, v.x, a));
    const float e1 = __expf(fmaf(100.f, v.y, a));
    const float e2 = __expf(fmaf(100.f, v.z, a));
    const float e3 = __expf(fmaf(100.f, v.w, a));
    const float esum = (e0 + e1) + (e2 + e3);
    se += esum;
    sy = fmaf(esum, (float)h, sy);
    sx += fmaf(esum, (float)w0, fmaf(2.f, e2, fmaf(3.f, e3, e1)));
  }

  // In-wave combine: rescale partials to the wave max, then sum.
  const float M = waveMax(m);
  const float fw = __expf(100.f * (m - M));
  se = waveSum(se * fw);
  sx = waveSum(sx * fw);
  sy = waveSum(sy * fw);

  __shared__ float s[4][4];
  const int wid = t >> 6, lane = t & 63;
  if (lane == 0) { s[wid][0] = M; s[wid][1] = se; s[wid][2] = sx; s[wid][3] = sy; }
  __syncthreads();
  if (t == 0) {
    const float MM = fmaxf(fmaxf(s[0][0], s[1][0]), fmaxf(s[2][0], s[3][0]));
    float SE = 0.f, SX = 0.f, SY = 0.f;
#pragma unroll
    for (int i = 0; i < 4; ++i) {
      const float f = __expf(100.f * (s[i][0] - MM));
      SE = fmaf(s[i][1], f, SE);
      SX = fmaf(s[i][2], f, SX);
      SY = fmaf(s[i][3], f, SY);
    }
    // reference: scale = [H_img/Hh, W_img/Wh] applied to (kx, ky) in order
    const float scx = (float)Hp[0] / (float)HH;
    const float scy = (float)Wp[0] / (float)WW;
    ((float2*)kp)[r] = make_float2(SX / SE * scx, SY / SE * scy);
  }
}

// One thread per (b, j): M = A^T A (double), Jacobi eigen 4x4, min eigvec.
__global__ __launch_bounds__(256) void dlt_k(
    const float* __restrict__ P, const float* __restrict__ conf,
    const float* __restrict__ kp, float* __restrict__ out) {
  const int idx = blockIdx.x * blockDim.x + threadIdx.x;
  if (idx >= B_NUM * J_NUM) return;
  const int b = idx / J_NUM;
  const int j = idx - b * J_NUM;

  double M[4][4];
#pragma unroll
  for (int a = 0; a < 4; ++a)
#pragma unroll
    for (int bb = 0; bb < 4; ++bb) M[a][bb] = 0.0;

#pragma unroll
  for (int c = 0; c < C_NUM; ++c) {
    const float* Pm = P + ((size_t)(b * C_NUM + c)) * 12;
    const float cf = conf[(b * C_NUM + c) * J_NUM + j];
    const float2 xy = ((const float2*)kp)[(b * C_NUM + c) * J_NUM + j];
    double row0[4], row1[4];
#pragma unroll
    for (int l = 0; l < 4; ++l) {
      const double p2 = (double)Pm[8 + l];
      row0[l] = (p2 * (double)xy.x - (double)Pm[l]) * (double)cf;
      row1[l] = (p2 * (double)xy.y - (double)Pm[4 + l]) * (double)cf;
    }
#pragma unroll
    for (int a = 0; a < 4; ++a)
#pragma unroll
      for (int bb = 0; bb < 4; ++bb)
        M[a][bb] += row0[a] * row0[bb] + row1[a] * row1[bb];
  }

  double V[4][4];
#pragma unroll
  for (int a = 0; a < 4; ++a)
#pragma unroll
    for (int bb = 0; bb < 4; ++bb) V[a][bb] = (a == bb) ? 1.0 : 0.0;

  for (int sweep = 0; sweep < 8; ++sweep) {
#pragma unroll
    for (int p = 0; p < 3; ++p) {
#pragma unroll
      for (int q = p + 1; q < 4; ++q) {
        const double d = M[p][q];
        if (fabs(d) < 1e-300) continue;
        const double a = M[p][p], bq = M[q][q];
        const double theta = (bq - a) / (2.0 * d);
        const double tt = (theta >= 0.0 ? 1.0 : -1.0) /
                          (fabs(theta) + sqrt(theta * theta + 1.0));
        const double cc = 1.0 / sqrt(tt * tt + 1.0);
        const double ss = tt * cc;
#pragma unroll
        for (int k = 0; k < 4; ++k) {
          if (k == p || k == q) continue;
          const double mkp = M[k][p], mkq = M[k][q];
          M[k][p] = M[p][k] = cc * mkp - ss * mkq;
          M[k][q] = M[q][k] = ss * mkp + cc * mkq;
        }
        M[p][p] = a - tt * d;
        M[q][q] = bq + tt * d;
        M[p][q] = M[q][p] = 0.0;
#pragma unroll
        for (int k = 0; k < 4; ++k) {
          const double vkp = V[k][p], vkq = V[k][q];
          V[k][p] = cc * vkp - ss * vkq;
          V[k][q] = ss * vkp + cc * vkq;
        }
      }
    }
  }

  int mi = 0;
  double mv = M[0][0];
#pragma unroll
  for (int i = 1; i < 4; ++i)
    if (M[i][i] < mv) { mv = M[i][i]; mi = i; }
  const double h3 = V[3][mi];
  out[idx * 3 + 0] = (float)(V[0][mi] / h3);
  out[idx * 3 + 1] = (float)(V[1][mi] / h3);
  out[idx * 3 + 2] = (float)(V[2][mi] / h3);
}

extern "C" void kernel_launch(void* const* d_in, const int* in_sizes, int n_in,
                              void* d_out, int out_size, void* d_ws, size_t ws_size,
                              hipStream_t stream) {
  const float* hm = (const float*)d_in[0];
  const float* P = (const float*)d_in[1];
  const float* conf = (const float*)d_in[2];
  const int* Hp = (const int*)d_in[3];
  const int* Wp = (const int*)d_in[4];
  float* out = (float*)d_out;
  float* kp = (float*)d_ws;  // 4352 float2 keypoints

  softargmax_k<<<B_NUM * C_NUM * J_NUM, 256, 0, stream>>>(hm, Hp, Wp, kp);
  dlt_k<<<(B_NUM * J_NUM + 255) / 256, 256, 0, stream>>>(P, conf, kp, out);
}